// Round 10
// baseline (257.730 us; speedup 1.0000x reference)
//
#include <hip/hip_runtime.h>
#include <hip/hip_bf16.h>

// LSTM autoencoder: B=4096, T=128, F=32, H=64, 4H=256.
// One block per 16 batch rows (grid=256, 1 block/CU). 4 waves; wave w owns
// gate columns {i,f,g,o} x [16w,16w+16) so the cell update is pure per-lane.
//
// NUMERICS: 3-plane bf16 split for h, x, U, W; 6-term products -> ~2^-22
// per-step injection, absmax ~1e7 vs 1.15e8 threshold (10x margin, robust
// to reassociation). -log2e folded into i/f/o weights+bias, sigmoid =
// rcp(1+exp2(z)), fused-asm LDS-only barrier (no vmcnt drain).
//
// ROUND 10: break MFMA accumulator dependency chains. Round 9 counters:
// MfmaUtil 40% + VALUBusy 37%, 1 wave/SIMD -> serial phases; the MFMA phase
// ran ~1060cyc for 72 MFMAs (issue floor ~360) because each gate was ONE
// 18-deep chain (only 4 chains in flight vs ~30-40cyc dep latency). Now each
// gate = 3 independent chains of 6 (x@W, ha0@U0, ha1@U1) summed at the end:
// 12 chains in flight -> issue-bound MFMA phase.

typedef __bf16 bf16x8 __attribute__((ext_vector_type(8)));
typedef float f32x4 __attribute__((ext_vector_type(4)));
typedef float f32x8 __attribute__((ext_vector_type(8)));

struct frag3 { bf16x8 p1, p2, p3; };
struct bf3 { __bf16 a, b, c; };

#define NEG_LOG2E (-1.44269504088896340736f)

// sigmoid(pre) where z = -log2e * pre came out of the scaled MFMA
__device__ __forceinline__ float fast_sig(float z) {
    return __builtin_amdgcn_rcpf(1.0f + __builtin_amdgcn_exp2f(z));
}

// LDS-only barrier: waitcnt+barrier fused in ONE asm (compiler memory fence
// both sides, no vmcnt drain -> x prefetch / out stores stay in flight)
__device__ __forceinline__ void hbar() {
    asm volatile("s_waitcnt lgkmcnt(0)\n\ts_barrier" ::: "memory");
}

// 6-term double-double-style MFMA product: keeps all cross terms >= 2^-24
__device__ __forceinline__ f32x4 mfma6(const frag3& a, const frag3& b, f32x4 c) {
    c = __builtin_amdgcn_mfma_f32_16x16x32_bf16(a.p1, b.p1, c, 0, 0, 0);
    c = __builtin_amdgcn_mfma_f32_16x16x32_bf16(a.p1, b.p2, c, 0, 0, 0);
    c = __builtin_amdgcn_mfma_f32_16x16x32_bf16(a.p2, b.p1, c, 0, 0, 0);
    c = __builtin_amdgcn_mfma_f32_16x16x32_bf16(a.p2, b.p2, c, 0, 0, 0);
    c = __builtin_amdgcn_mfma_f32_16x16x32_bf16(a.p1, b.p3, c, 0, 0, 0);
    c = __builtin_amdgcn_mfma_f32_16x16x32_bf16(a.p3, b.p1, c, 0, 0, 0);
    return c;
}

// 3-term product (output-stage only, error doesn't compound)
__device__ __forceinline__ f32x4 mfma3(const frag3& a, const frag3& b, f32x4 c) {
    c = __builtin_amdgcn_mfma_f32_16x16x32_bf16(a.p1, b.p1, c, 0, 0, 0);
    c = __builtin_amdgcn_mfma_f32_16x16x32_bf16(a.p1, b.p2, c, 0, 0, 0);
    c = __builtin_amdgcn_mfma_f32_16x16x32_bf16(a.p2, b.p1, c, 0, 0, 0);
    return c;
}

__device__ __forceinline__ bf3 split3(float v) {
    bf3 r;
    r.a = (__bf16)v;
    float r1 = v - (float)r.a;
    r.b = (__bf16)r1;
    r.c = (__bf16)(r1 - (float)r.b);
    return r;
}

// 3-plane B-fragment of a [K x LD] row-major fp32 matrix, scaled before split:
// lane l, elem e -> scale * M[k0 + (l>>4)*8 + e][col]
template<int LD>
__device__ __forceinline__ frag3 load_fragB3(const float* __restrict__ M,
                                             int k0, int col, int lq,
                                             float scale) {
    frag3 r;
    const float* p = M + (size_t)(k0 + lq * 8) * LD + col;
#pragma unroll
    for (int e = 0; e < 8; ++e) {
        bf3 s = split3(p[(size_t)e * LD] * scale);
        r.p1[e] = s.a; r.p2[e] = s.b; r.p3[e] = s.c;
    }
    return r;
}

__device__ __forceinline__ frag3 split3_vec(f32x8 v) {
    frag3 r;
#pragma unroll
    for (int e = 0; e < 8; ++e) {
        bf3 s = split3(v[e]);
        r.p1[e] = s.a; r.p2[e] = s.b; r.p3[e] = s.c;
    }
    return r;
}

// swizzled byte offset inside one 16x64 bf16 h-tile (row = batch, 128B/row)
__device__ __forceinline__ int swz(int row, int byteoff) {
    return row * 128 + (byteoff ^ ((row & 7) << 4));
}

__global__ __launch_bounds__(256, 1)
void lstm_ae_kernel(const float* __restrict__ x,
                    const float* __restrict__ eW, const float* __restrict__ eU,
                    const float* __restrict__ eb,
                    const float* __restrict__ dW, const float* __restrict__ dU,
                    const float* __restrict__ db,
                    const float* __restrict__ nW, const float* __restrict__ nb,
                    float* __restrict__ out)
{
    const int tid = threadIdx.x;
    const int wv  = tid >> 6;        // wave 0..3
    const int ln  = tid & 63;
    const int l16 = ln & 15;
    const int lq  = ln >> 4;         // 0..3
    const int b0  = blockIdx.x << 4; // 16 batch rows per block
    const int wcol = wv * 16 + l16;  // this wave's column within each gate

    // [buffer][plane1..3] of a 16x64 bf16 h-tile, XOR-swizzled
    __shared__ __align__(16) unsigned char hraw[2][3][2048];

    // loop-invariant LDS byte offsets for h exchange
    int offw[4];
#pragma unroll
    for (int r = 0; r < 4; ++r) offw[r] = swz(lq * 4 + r, wcol * 2);
    const int offr0 = swz(l16, lq * 16);
    const int offr1 = swz(l16, 64 + lq * 16);

    // gate scales: sigmoid gates get -log2e folded in; relu gate (g=2) doesn't
    const float gscale[4] = {NEG_LOG2E, NEG_LOG2E, 1.0f, NEG_LOG2E};

    // ---------------- encoder weights (3-plane register fragments) ----------
    frag3 W3[4], U3[4][2];
    float bz[4];
#pragma unroll
    for (int g = 0; g < 4; ++g) {
        W3[g]    = load_fragB3<256>(eW, 0,  g * 64 + wcol, lq, gscale[g]);
        U3[g][0] = load_fragB3<256>(eU, 0,  g * 64 + wcol, lq, gscale[g]);
        U3[g][1] = load_fragB3<256>(eU, 32, g * 64 + wcol, lq, gscale[g]);
        bz[g]    = eb[g * 64 + wcol] * gscale[g];
    }

    const f32x4 zero4 = {0.f, 0.f, 0.f, 0.f};
    f32x4 cs = zero4;
    frag3 ha0, ha1;
#pragma unroll
    for (int e = 0; e < 8; ++e) {
        ha0.p1[e] = (__bf16)0.f; ha0.p2[e] = (__bf16)0.f; ha0.p3[e] = (__bf16)0.f;
        ha1.p1[e] = (__bf16)0.f; ha1.p2[e] = (__bf16)0.f; ha1.p3[e] = (__bf16)0.f;
    }

    // 2-deep x prefetch pipeline (barrier never drains vmcnt)
    const float* xbase = x + (size_t)(b0 + l16) * (128 * 32) + lq * 8;
    f32x8 xv0 = *(const f32x8*)(xbase);
    f32x8 xv1 = *(const f32x8*)(xbase + 32);

    int q = 0;
    // ---------------- encoder scan ----------------
#pragma unroll 2
    for (int t = 0; t < 128; ++t) {
        const int tn = (t + 2 < 128) ? (t + 2) : 127;
        f32x8 xv2 = *(const f32x8*)(xbase + (size_t)tn * 32);

        frag3 xa3 = split3_vec(xv0);

        // 12 independent accumulator chains (3 per gate, depth 6)
        f32x4 a0[4], a1[4], a2[4];
#pragma unroll
        for (int g = 0; g < 4; ++g) {
            f32x4 zb = {bz[g], bz[g], bz[g], bz[g]};
            a0[g] = mfma6(xa3, W3[g],    zb);
            a1[g] = mfma6(ha0, U3[g][0], zero4);
            a2[g] = mfma6(ha1, U3[g][1], zero4);
        }
        f32x4 z[4];
#pragma unroll
        for (int g = 0; g < 4; ++g) z[g] = (a0[g] + a1[g]) + a2[g];
#pragma unroll
        for (int r = 0; r < 4; ++r) {
            float ig = fast_sig(z[0][r]);
            float fg = fast_sig(z[1][r]);
            float gg = fmaxf(z[2][r], 0.f);
            float og = fast_sig(z[3][r]);
            cs[r] = fg * cs[r] + ig * gg;
            float hv = og * fmaxf(cs[r], 0.f);
            bf3 s = split3(hv);
            *(__bf16*)(hraw[q][0] + offw[r]) = s.a;
            *(__bf16*)(hraw[q][1] + offw[r]) = s.b;
            *(__bf16*)(hraw[q][2] + offw[r]) = s.c;
        }
        hbar();
        ha0.p1 = *(const bf16x8*)(hraw[q][0] + offr0);
        ha0.p2 = *(const bf16x8*)(hraw[q][1] + offr0);
        ha0.p3 = *(const bf16x8*)(hraw[q][2] + offr0);
        ha1.p1 = *(const bf16x8*)(hraw[q][0] + offr1);
        ha1.p2 = *(const bf16x8*)(hraw[q][1] + offr1);
        ha1.p3 = *(const bf16x8*)(hraw[q][2] + offr1);
        q ^= 1;
        xv0 = xv1; xv1 = xv2;
    }
    // ha0/ha1 now hold the encoded state (3-plane A-fragments).

    // ------- decoder constant input projection zx = encoded@dW + db -------
    frag3 dU3[4][2];
    f32x4 zx[4];
#pragma unroll
    for (int g = 0; g < 4; ++g) {
        frag3 w0 = load_fragB3<256>(dW, 0,  g * 64 + wcol, lq, gscale[g]);
        frag3 w1 = load_fragB3<256>(dW, 32, g * 64 + wcol, lq, gscale[g]);
        dU3[g][0] = load_fragB3<256>(dU, 0,  g * 64 + wcol, lq, gscale[g]);
        dU3[g][1] = load_fragB3<256>(dU, 32, g * 64 + wcol, lq, gscale[g]);
        float bb = db[g * 64 + wcol] * gscale[g];
        f32x4 zc = {bb, bb, bb, bb};
        zc = mfma6(ha0, w0, zc);
        zc = mfma6(ha1, w1, zc);
        zx[g] = zc;
    }
    // dense weights (waves 0,1: N-tiles of 16 over F=32); output stage ->
    // 3-term is plenty (no compounding)
    frag3 DN3[2];
    float ob = 0.f;
    if (wv < 2) {
        DN3[0] = load_fragB3<32>(nW, 0,  wv * 16 + l16, lq, 1.0f);
        DN3[1] = load_fragB3<32>(nW, 32, wv * 16 + l16, lq, 1.0f);
        ob     = nb[wv * 16 + l16];
    }

#pragma unroll
    for (int e = 0; e < 8; ++e) {
        ha0.p1[e] = (__bf16)0.f; ha0.p2[e] = (__bf16)0.f; ha0.p3[e] = (__bf16)0.f;
        ha1.p1[e] = (__bf16)0.f; ha1.p2[e] = (__bf16)0.f; ha1.p3[e] = (__bf16)0.f;
    }
    cs = zero4;
    q = 0;
    // ---------------- decoder scan + fused dense ----------------
#pragma unroll 2
    for (int t = 0; t < 128; ++t) {
        // 8 independent accumulator chains (2 per gate, depth 6)
        f32x4 a0[4], a1[4];
#pragma unroll
        for (int g = 0; g < 4; ++g) {
            a0[g] = mfma6(ha0, dU3[g][0], zx[g]);
            a1[g] = mfma6(ha1, dU3[g][1], zero4);
        }
        f32x4 z[4];
#pragma unroll
        for (int g = 0; g < 4; ++g) z[g] = a0[g] + a1[g];
#pragma unroll
        for (int r = 0; r < 4; ++r) {
            float ig = fast_sig(z[0][r]);
            float fg = fast_sig(z[1][r]);
            float gg = fmaxf(z[2][r], 0.f);
            float og = fast_sig(z[3][r]);
            cs[r] = fg * cs[r] + ig * gg;
            float hv = og * fmaxf(cs[r], 0.f);
            bf3 s = split3(hv);
            *(__bf16*)(hraw[q][0] + offw[r]) = s.a;
            *(__bf16*)(hraw[q][1] + offw[r]) = s.b;
            *(__bf16*)(hraw[q][2] + offw[r]) = s.c;
        }
        hbar();
        ha0.p1 = *(const bf16x8*)(hraw[q][0] + offr0);
        ha0.p2 = *(const bf16x8*)(hraw[q][1] + offr0);
        ha0.p3 = *(const bf16x8*)(hraw[q][2] + offr0);
        ha1.p1 = *(const bf16x8*)(hraw[q][0] + offr1);
        ha1.p2 = *(const bf16x8*)(hraw[q][1] + offr1);
        ha1.p3 = *(const bf16x8*)(hraw[q][2] + offr1);
        // fused dense: out[b][t][:] = h_t @ nW + nb  (2 chains + add)
        if (wv < 2) {
            f32x4 ob4 = {ob, ob, ob, ob};
            f32x4 d0 = mfma3(ha0, DN3[0], ob4);
            f32x4 d1 = mfma3(ha1, DN3[1], zero4);
            f32x4 oa = d0 + d1;
#pragma unroll
            for (int r = 0; r < 4; ++r)
                out[((size_t)(b0 + lq * 4 + r) * 128 + t) * 32 + wv * 16 + l16] = oa[r];
        }
        q ^= 1;
    }
}

extern "C" void kernel_launch(void* const* d_in, const int* in_sizes, int n_in,
                              void* d_out, int out_size, void* d_ws, size_t ws_size,
                              hipStream_t stream) {
    const float* x  = (const float*)d_in[0];
    const float* eW = (const float*)d_in[1];
    const float* eU = (const float*)d_in[2];
    const float* eb = (const float*)d_in[3];
    const float* dW = (const float*)d_in[4];
    const float* dU = (const float*)d_in[5];
    const float* db = (const float*)d_in[6];
    const float* nW = (const float*)d_in[7];
    const float* nb = (const float*)d_in[8];
    float* out = (float*)d_out;

    hipLaunchKernelGGL(lstm_ae_kernel, dim3(4096 / 16), dim3(256), 0, stream,
                       x, eW, eU, eb, dW, dU, db, nW, nb, out);
}

// Round 11
// 254.943 us; speedup vs baseline: 1.0109x; 1.0109x over previous
//
#include <hip/hip_runtime.h>
#include <hip/hip_bf16.h>

// LSTM autoencoder: B=4096, T=128, F=32, H=64, 4H=256.
// ROUND 11: 8 waves (512 thr), grid 256 (1 block/CU). SIMD s hosts waves s
// (lo) and s+4 (hi) — a producer PAIR splitting the same pair-column work:
//   encoder: lo = xW(all 4 gates) + hU-slice0(gates i,f)   [36 MFMAs]
//            hi = hU-slice0(gates g,o) + hU-slice1(all)    [36 MFMAs]
//   decoder: lo = dU-slice0(all)+zx, hi = dU-slice1(all) + fused dense (w4,5)
// Partial z exchanged via lane-contiguous LDS zbuf; ROW-SPLIT gate math
// (lo: C-rows lq*4+{0,1}, hi: +{2,3}) halves VALU/wave; 2 fused-asm
// LDS-only barriers/step. Role branch forced SCALAR via readfirstlane
// (exec-mask fallback would serialize the arms and break pairing).
// Round 10 showed MFMA is throughput-bound/SIMD (~19cy each): same total
// MFMA, but now VALU of one wave overlaps MFMA of the other.
// NUMERICS unchanged: 3-plane bf16 split, 6-term products (~2^-22/step),
// -log2e folded into i/f/o weights, sigmoid=rcp(1+exp2(z)). absmax floor
// ~1e7 vs 1.15e8 threshold — robust to this reassociation.

typedef __bf16 bf16x8 __attribute__((ext_vector_type(8)));
typedef float f32x4 __attribute__((ext_vector_type(4)));
typedef float f32x8 __attribute__((ext_vector_type(8)));

struct frag3 { bf16x8 p1, p2, p3; };
struct bf3 { __bf16 a, b, c; };

#define NEG_LOG2E (-1.44269504088896340736f)

__device__ __forceinline__ float fast_sig(float z) {
    return __builtin_amdgcn_rcpf(1.0f + __builtin_amdgcn_exp2f(z));
}

// LDS-only barrier: waitcnt+barrier fused in ONE asm (compiler memory fence
// both sides, no vmcnt drain -> x prefetch / out stores stay in flight)
__device__ __forceinline__ void hbar() {
    asm volatile("s_waitcnt lgkmcnt(0)\n\ts_barrier" ::: "memory");
}

__device__ __forceinline__ f32x4 mfma6(const frag3& a, const frag3& b, f32x4 c) {
    c = __builtin_amdgcn_mfma_f32_16x16x32_bf16(a.p1, b.p1, c, 0, 0, 0);
    c = __builtin_amdgcn_mfma_f32_16x16x32_bf16(a.p1, b.p2, c, 0, 0, 0);
    c = __builtin_amdgcn_mfma_f32_16x16x32_bf16(a.p2, b.p1, c, 0, 0, 0);
    c = __builtin_amdgcn_mfma_f32_16x16x32_bf16(a.p2, b.p2, c, 0, 0, 0);
    c = __builtin_amdgcn_mfma_f32_16x16x32_bf16(a.p1, b.p3, c, 0, 0, 0);
    c = __builtin_amdgcn_mfma_f32_16x16x32_bf16(a.p3, b.p1, c, 0, 0, 0);
    return c;
}

// 3-term product (output dense only; error doesn't compound)
__device__ __forceinline__ f32x4 mfma3(const frag3& a, const frag3& b, f32x4 c) {
    c = __builtin_amdgcn_mfma_f32_16x16x32_bf16(a.p1, b.p1, c, 0, 0, 0);
    c = __builtin_amdgcn_mfma_f32_16x16x32_bf16(a.p1, b.p2, c, 0, 0, 0);
    c = __builtin_amdgcn_mfma_f32_16x16x32_bf16(a.p2, b.p1, c, 0, 0, 0);
    return c;
}

__device__ __forceinline__ bf3 split3(float v) {
    bf3 r;
    r.a = (__bf16)v;
    float r1 = v - (float)r.a;
    r.b = (__bf16)r1;
    r.c = (__bf16)(r1 - (float)r.b);
    return r;
}

template<int LD>
__device__ __forceinline__ frag3 load_fragB3(const float* __restrict__ M,
                                             int k0, int col, int lq,
                                             float scale) {
    frag3 r;
    const float* p = M + (size_t)(k0 + lq * 8) * LD + col;
#pragma unroll
    for (int e = 0; e < 8; ++e) {
        bf3 s = split3(p[(size_t)e * LD] * scale);
        r.p1[e] = s.a; r.p2[e] = s.b; r.p3[e] = s.c;
    }
    return r;
}

__device__ __forceinline__ frag3 split3_vec(f32x8 v) {
    frag3 r;
#pragma unroll
    for (int e = 0; e < 8; ++e) {
        bf3 s = split3(v[e]);
        r.p1[e] = s.a; r.p2[e] = s.b; r.p3[e] = s.c;
    }
    return r;
}

__device__ __forceinline__ frag3 zfrag() {
    frag3 r;
#pragma unroll
    for (int e = 0; e < 8; ++e) {
        r.p1[e] = (__bf16)0.f; r.p2[e] = (__bf16)0.f; r.p3[e] = (__bf16)0.f;
    }
    return r;
}

// swizzled byte offset inside one 16x64 bf16 h-tile (row = batch, 128B/row)
__device__ __forceinline__ int swz(int row, int byteoff) {
    return row * 128 + (byteoff ^ ((row & 7) << 4));
}

__global__ __launch_bounds__(512, 1)
void lstm_ae_kernel(const float* __restrict__ x,
                    const float* __restrict__ eW, const float* __restrict__ eU,
                    const float* __restrict__ eb,
                    const float* __restrict__ dW, const float* __restrict__ dU,
                    const float* __restrict__ db,
                    const float* __restrict__ nW, const float* __restrict__ nb,
                    float* __restrict__ out)
{
    const int tid = threadIdx.x;
    const int wv  = tid >> 6;        // 0..7
    const int ln  = tid & 63;
    const int l16 = ln & 15;
    const int lq  = ln >> 4;
    const int pr  = wv & 3;          // pair id
    const int b0  = blockIdx.x << 4; // 16 batch rows per block
    const int wcol = pr * 16 + l16;
    // scalar role: 0 = waves 0-3 (lo), 1 = waves 4-7 (hi)
    const int role = __builtin_amdgcn_readfirstlane(tid >> 8);
    const int roleoff = role * 2;

    // single-buffered h planes (safe: 2 barriers/step, reads drained by hbar)
    __shared__ __align__(16) unsigned char hraw[3][2048];
    // partial-z exchange: [pair][writer-role][r2][gate][lane] lane-contiguous
    __shared__ float zbuf[4][2][2][4][64];

    int offwr[2];
#pragma unroll
    for (int r2 = 0; r2 < 2; ++r2)
        offwr[r2] = swz(lq * 4 + roleoff + r2, wcol * 2);
    const int offr0 = swz(l16, lq * 16);
    const int offr1 = swz(l16, 64 + lq * 16);

    const float gscale[4] = {NEG_LOG2E, NEG_LOG2E, 1.0f, NEG_LOG2E};
    const f32x4 zero4 = {0.f, 0.f, 0.f, 0.f};

    if (role == 0) {
        // ================= LO path =================
        // -------- encoder: xW(all) + hU0(gates 0,1); gate rows {0,1} --------
        frag3 W3[4], U3a[2];
        float bz[4];
#pragma unroll
        for (int g = 0; g < 4; ++g) {
            W3[g] = load_fragB3<256>(eW, 0, g * 64 + wcol, lq, gscale[g]);
            bz[g] = eb[g * 64 + wcol] * gscale[g];
        }
        U3a[0] = load_fragB3<256>(eU, 0, 0 * 64 + wcol, lq, gscale[0]);
        U3a[1] = load_fragB3<256>(eU, 0, 1 * 64 + wcol, lq, gscale[1]);

        frag3 ha0 = zfrag();
        float cs2[2] = {0.f, 0.f};

        const float* xbase = x + (size_t)(b0 + l16) * (128 * 32) + lq * 8;
        f32x8 xv0 = *(const f32x8*)(xbase);
        f32x8 xv1 = *(const f32x8*)(xbase + 32);

#pragma unroll 1
        for (int t = 0; t < 128; ++t) {
            const int tn = (t + 2 < 128) ? (t + 2) : 127;
            f32x8 xv2 = *(const f32x8*)(xbase + (size_t)tn * 32);
            frag3 xa3 = split3_vec(xv0);

            f32x4 acc[4];
#pragma unroll
            for (int g = 0; g < 4; ++g) {
                f32x4 a = {bz[g], bz[g], bz[g], bz[g]};
                acc[g] = mfma6(xa3, W3[g], a);
            }
            acc[0] = mfma6(ha0, U3a[0], acc[0]);
            acc[1] = mfma6(ha0, U3a[1], acc[1]);

#pragma unroll
            for (int r2 = 0; r2 < 2; ++r2)
#pragma unroll
                for (int g = 0; g < 4; ++g)
                    zbuf[pr][0][r2][g][ln] = acc[g][2 + r2]; // partner's rows
            hbar();
#pragma unroll
            for (int r2 = 0; r2 < 2; ++r2) {
                float zi = acc[0][r2] + zbuf[pr][1][r2][0][ln];
                float zf = acc[1][r2] + zbuf[pr][1][r2][1][ln];
                float zg = acc[2][r2] + zbuf[pr][1][r2][2][ln];
                float zo = acc[3][r2] + zbuf[pr][1][r2][3][ln];
                float ig = fast_sig(zi), fg = fast_sig(zf), og = fast_sig(zo);
                float gg = fmaxf(zg, 0.f);
                cs2[r2] = fg * cs2[r2] + ig * gg;
                float hv = og * fmaxf(cs2[r2], 0.f);
                bf3 s = split3(hv);
                *(__bf16*)(hraw[0] + offwr[r2]) = s.a;
                *(__bf16*)(hraw[1] + offwr[r2]) = s.b;
                *(__bf16*)(hraw[2] + offwr[r2]) = s.c;
            }
            hbar();
            ha0.p1 = *(const bf16x8*)(hraw[0] + offr0);
            ha0.p2 = *(const bf16x8*)(hraw[1] + offr0);
            ha0.p3 = *(const bf16x8*)(hraw[2] + offr0);
            xv0 = xv1; xv1 = xv2;
        }

        // -------- transition: zx = encoded@dW + db (6-term), dU slice0 -------
        frag3 e0, e1;
        e0.p1 = *(const bf16x8*)(hraw[0] + offr0);
        e0.p2 = *(const bf16x8*)(hraw[1] + offr0);
        e0.p3 = *(const bf16x8*)(hraw[2] + offr0);
        e1.p1 = *(const bf16x8*)(hraw[0] + offr1);
        e1.p2 = *(const bf16x8*)(hraw[1] + offr1);
        e1.p3 = *(const bf16x8*)(hraw[2] + offr1);
        f32x4 zx[4];
        frag3 dU0[4];
#pragma unroll
        for (int g = 0; g < 4; ++g) {
            frag3 w0 = load_fragB3<256>(dW, 0,  g * 64 + wcol, lq, gscale[g]);
            frag3 w1 = load_fragB3<256>(dW, 32, g * 64 + wcol, lq, gscale[g]);
            float bb = db[g * 64 + wcol] * gscale[g];
            f32x4 a = {bb, bb, bb, bb};
            a = mfma6(e0, w0, a);
            a = mfma6(e1, w1, a);
            zx[g] = a;
            dU0[g] = load_fragB3<256>(dU, 0, g * 64 + wcol, lq, gscale[g]);
        }

        // -------- decoder: dU slice0; gate rows {0,1} --------
        frag3 hd0 = zfrag();
        cs2[0] = cs2[1] = 0.f;
#pragma unroll 1
        for (int t = 0; t < 128; ++t) {
            f32x4 acc[4];
#pragma unroll
            for (int g = 0; g < 4; ++g) acc[g] = mfma6(hd0, dU0[g], zx[g]);
#pragma unroll
            for (int r2 = 0; r2 < 2; ++r2)
#pragma unroll
                for (int g = 0; g < 4; ++g)
                    zbuf[pr][0][r2][g][ln] = acc[g][2 + r2];
            hbar();
#pragma unroll
            for (int r2 = 0; r2 < 2; ++r2) {
                float zi = acc[0][r2] + zbuf[pr][1][r2][0][ln];
                float zf = acc[1][r2] + zbuf[pr][1][r2][1][ln];
                float zg = acc[2][r2] + zbuf[pr][1][r2][2][ln];
                float zo = acc[3][r2] + zbuf[pr][1][r2][3][ln];
                float ig = fast_sig(zi), fg = fast_sig(zf), og = fast_sig(zo);
                float gg = fmaxf(zg, 0.f);
                cs2[r2] = fg * cs2[r2] + ig * gg;
                float hv = og * fmaxf(cs2[r2], 0.f);
                bf3 s = split3(hv);
                *(__bf16*)(hraw[0] + offwr[r2]) = s.a;
                *(__bf16*)(hraw[1] + offwr[r2]) = s.b;
                *(__bf16*)(hraw[2] + offwr[r2]) = s.c;
            }
            hbar();
            hd0.p1 = *(const bf16x8*)(hraw[0] + offr0);
            hd0.p2 = *(const bf16x8*)(hraw[1] + offr0);
            hd0.p3 = *(const bf16x8*)(hraw[2] + offr0);
        }
    } else {
        // ================= HI path =================
        // -------- encoder: hU0(gates 2,3) + hU1(all); gate rows {2,3} --------
        frag3 U3b[2], U3c[4];
        U3b[0] = load_fragB3<256>(eU, 0, 2 * 64 + wcol, lq, gscale[2]);
        U3b[1] = load_fragB3<256>(eU, 0, 3 * 64 + wcol, lq, gscale[3]);
#pragma unroll
        for (int g = 0; g < 4; ++g)
            U3c[g] = load_fragB3<256>(eU, 32, g * 64 + wcol, lq, gscale[g]);

        frag3 ha0 = zfrag(), ha1 = zfrag();
        float cs2[2] = {0.f, 0.f};

#pragma unroll 1
        for (int t = 0; t < 128; ++t) {
            f32x4 acc[4];
            acc[0] = mfma6(ha1, U3c[0], zero4);
            acc[1] = mfma6(ha1, U3c[1], zero4);
            acc[2] = mfma6(ha0, U3b[0], zero4);
            acc[2] = mfma6(ha1, U3c[2], acc[2]);
            acc[3] = mfma6(ha0, U3b[1], zero4);
            acc[3] = mfma6(ha1, U3c[3], acc[3]);

#pragma unroll
            for (int r2 = 0; r2 < 2; ++r2)
#pragma unroll
                for (int g = 0; g < 4; ++g)
                    zbuf[pr][1][r2][g][ln] = acc[g][r2]; // partner's rows {0,1}
            hbar();
#pragma unroll
            for (int r2 = 0; r2 < 2; ++r2) {
                float zi = acc[0][2 + r2] + zbuf[pr][0][r2][0][ln];
                float zf = acc[1][2 + r2] + zbuf[pr][0][r2][1][ln];
                float zg = acc[2][2 + r2] + zbuf[pr][0][r2][2][ln];
                float zo = acc[3][2 + r2] + zbuf[pr][0][r2][3][ln];
                float ig = fast_sig(zi), fg = fast_sig(zf), og = fast_sig(zo);
                float gg = fmaxf(zg, 0.f);
                cs2[r2] = fg * cs2[r2] + ig * gg;
                float hv = og * fmaxf(cs2[r2], 0.f);
                bf3 s = split3(hv);
                *(__bf16*)(hraw[0] + offwr[r2]) = s.a;
                *(__bf16*)(hraw[1] + offwr[r2]) = s.b;
                *(__bf16*)(hraw[2] + offwr[r2]) = s.c;
            }
            hbar();
            ha0.p1 = *(const bf16x8*)(hraw[0] + offr0);
            ha0.p2 = *(const bf16x8*)(hraw[1] + offr0);
            ha0.p3 = *(const bf16x8*)(hraw[2] + offr0);
            ha1.p1 = *(const bf16x8*)(hraw[0] + offr1);
            ha1.p2 = *(const bf16x8*)(hraw[1] + offr1);
            ha1.p3 = *(const bf16x8*)(hraw[2] + offr1);
        }

        // -------- transition: dU slice1 (+ dense weights on waves 4,5) -------
        frag3 dU1[4];
#pragma unroll
        for (int g = 0; g < 4; ++g)
            dU1[g] = load_fragB3<256>(dU, 32, g * 64 + wcol, lq, gscale[g]);
        const bool dn = (wv < 6); // waves 4,5 do the fused dense
        frag3 DN0 = zfrag(), DN1 = zfrag(), hdd = zfrag();
        float obv = 0.f;
        if (dn) {
            DN0 = load_fragB3<32>(nW, 0,  (wv - 4) * 16 + l16, lq, 1.0f);
            DN1 = load_fragB3<32>(nW, 32, (wv - 4) * 16 + l16, lq, 1.0f);
            obv = nb[(wv - 4) * 16 + l16];
        }

        // -------- decoder: dU slice1; gate rows {2,3}; fused dense --------
        frag3 hd1 = zfrag();
        cs2[0] = cs2[1] = 0.f;
#pragma unroll 1
        for (int t = 0; t < 128; ++t) {
            f32x4 acc[4];
#pragma unroll
            for (int g = 0; g < 4; ++g) acc[g] = mfma6(hd1, dU1[g], zero4);
#pragma unroll
            for (int r2 = 0; r2 < 2; ++r2)
#pragma unroll
                for (int g = 0; g < 4; ++g)
                    zbuf[pr][1][r2][g][ln] = acc[g][r2];
            hbar();
#pragma unroll
            for (int r2 = 0; r2 < 2; ++r2) {
                float zi = acc[0][2 + r2] + zbuf[pr][0][r2][0][ln];
                float zf = acc[1][2 + r2] + zbuf[pr][0][r2][1][ln];
                float zg = acc[2][2 + r2] + zbuf[pr][0][r2][2][ln];
                float zo = acc[3][2 + r2] + zbuf[pr][0][r2][3][ln];
                float ig = fast_sig(zi), fg = fast_sig(zf), og = fast_sig(zo);
                float gg = fmaxf(zg, 0.f);
                cs2[r2] = fg * cs2[r2] + ig * gg;
                float hv = og * fmaxf(cs2[r2], 0.f);
                bf3 s = split3(hv);
                *(__bf16*)(hraw[0] + offwr[r2]) = s.a;
                *(__bf16*)(hraw[1] + offwr[r2]) = s.b;
                *(__bf16*)(hraw[2] + offwr[r2]) = s.c;
            }
            hbar();
            hd1.p1 = *(const bf16x8*)(hraw[0] + offr1);
            hd1.p2 = *(const bf16x8*)(hraw[1] + offr1);
            hd1.p3 = *(const bf16x8*)(hraw[2] + offr1);
            if (dn) {
                hdd.p1 = *(const bf16x8*)(hraw[0] + offr0);
                hdd.p2 = *(const bf16x8*)(hraw[1] + offr0);
                f32x4 oa = {obv, obv, obv, obv};
                oa = mfma3(hdd, DN0, oa);  // k = units 0..31
                oa = mfma3(hd1, DN1, oa);  // k = units 32..63
#pragma unroll
                for (int r = 0; r < 4; ++r)
                    out[((size_t)(b0 + lq * 4 + r) * 128 + t) * 32
                        + (wv - 4) * 16 + l16] = oa[r];
            }
        }
    }
}

extern "C" void kernel_launch(void* const* d_in, const int* in_sizes, int n_in,
                              void* d_out, int out_size, void* d_ws, size_t ws_size,
                              hipStream_t stream) {
    const float* x  = (const float*)d_in[0];
    const float* eW = (const float*)d_in[1];
    const float* eU = (const float*)d_in[2];
    const float* eb = (const float*)d_in[3];
    const float* dW = (const float*)d_in[4];
    const float* dU = (const float*)d_in[5];
    const float* db = (const float*)d_in[6];
    const float* nW = (const float*)d_in[7];
    const float* nb = (const float*)d_in[8];
    float* out = (float*)d_out;

    hipLaunchKernelGGL(lstm_ae_kernel, dim3(4096 / 16), dim3(512), 0, stream,
                       x, eW, eU, eb, dW, dU, db, nW, nb, out);
}